// Round 2
// baseline (2227.938 us; speedup 1.0000x reference)
//
#include <hip/hip_runtime.h>
#include <stdint.h>

#define N_ 2048
#define D_ 128
#define B_ 8
#define BT 128           // block tile
#define NT 16            // N_/BT
#define NPAIRS 136       // NT*(NT+1)/2 upper-triangle tile pairs
#define NBIN 1024
#define CAP 65536        // per-pair append capacity (expected ~24K)

typedef __attribute__((ext_vector_type(8))) short short8;
typedef __attribute__((ext_vector_type(4))) float f32x4;

// monotonic key: ascending uint order == ascending float order
__device__ __forceinline__ uint32_t fkey(float f) {
    uint32_t u = __float_as_uint(f);
    return (u & 0x80000000u) ? ~u : (u | 0x80000000u);
}
__device__ __forceinline__ float keyf(uint32_t k) {
    uint32_t u = (k & 0x80000000u) ? (k & 0x7fffffffu) : ~k;
    return __uint_as_float(u);
}
// f32 -> bf16 bits, round-to-nearest-even (finite inputs only)
__device__ __forceinline__ uint32_t bf16_rne(float x) {
    uint32_t u = __float_as_uint(x);
    return (u + 0x7fffu + ((u >> 16) & 1u)) >> 16;
}
// linear bin — MUST be the identical expression in hist and append passes
__device__ __forceinline__ int binof(float v, float R, float scl) {
    int b = (int)((v + R) * scl);
    if (b < 0) b = 0;
    if (b >= NBIN) b = NBIN - 1;
    return b;
}

struct Panels { ushort Ah[BT*32], Al[BT*32], Bh[BT*32], Bl[BT*32]; }; // 32 KB

// 128x128 tile (ti,tj) of Xb*Xb^T via split-bf16 MFMA (hi*hi + hi*lo + lo*hi).
// 4 waves (2x2), each wave 64x64 = 4x4 frags of 16x16x32.
// LDS panels [row][32k] bf16, 16B-slot swizzle: slot' = slot ^ ((row>>1)&3)  -> 2-way max.
__device__ __forceinline__ void compute_tile(const float* __restrict__ Xb,
        int ti, int tj, Panels& sm, f32x4 acc[4][4], int t)
{
    const int lane = t & 63;
    const int wv = t >> 6;
    const int wr = wv >> 1, wc = wv & 1;
    const int lr = lane & 15;     // row within 16-frag
    const int ls = lane >> 4;     // k-slot 0..3 (8 bf16 each)

    #pragma unroll
    for (int mm = 0; mm < 4; ++mm)
        #pragma unroll
        for (int nn = 0; nn < 4; ++nn)
            acc[mm][nn] = f32x4{0.f, 0.f, 0.f, 0.f};

    for (int kc = 0; kc < D_; kc += 32) {
        __syncthreads();   // also orders any pre-loop LDS init / prior readers
        #pragma unroll
        for (int i = 0; i < 4; ++i) {
            int q = t + 256*i;
            int row = q >> 3, f4 = q & 7;             // 8 float4 per row of 32 k
            float4 va = *(const float4*)&Xb[(size_t)(ti*BT + row)*D_ + kc + f4*4];
            float4 vb = *(const float4*)&Xb[(size_t)(tj*BT + row)*D_ + kc + f4*4];
            int sp  = (f4 >> 1) ^ ((row >> 1) & 3);
            int off = row*32 + sp*8 + (f4 & 1)*4;     // ushort units
            ushort4 h4, l4;
            {
                uint32_t h;
                h = bf16_rne(va.x); h4.x = (ushort)h; l4.x = (ushort)bf16_rne(va.x - __uint_as_float(h << 16));
                h = bf16_rne(va.y); h4.y = (ushort)h; l4.y = (ushort)bf16_rne(va.y - __uint_as_float(h << 16));
                h = bf16_rne(va.z); h4.z = (ushort)h; l4.z = (ushort)bf16_rne(va.z - __uint_as_float(h << 16));
                h = bf16_rne(va.w); h4.w = (ushort)h; l4.w = (ushort)bf16_rne(va.w - __uint_as_float(h << 16));
            }
            *(ushort4*)&sm.Ah[off] = h4;
            *(ushort4*)&sm.Al[off] = l4;
            {
                uint32_t h;
                h = bf16_rne(vb.x); h4.x = (ushort)h; l4.x = (ushort)bf16_rne(vb.x - __uint_as_float(h << 16));
                h = bf16_rne(vb.y); h4.y = (ushort)h; l4.y = (ushort)bf16_rne(vb.y - __uint_as_float(h << 16));
                h = bf16_rne(vb.z); h4.z = (ushort)h; l4.z = (ushort)bf16_rne(vb.z - __uint_as_float(h << 16));
                h = bf16_rne(vb.w); h4.w = (ushort)h; l4.w = (ushort)bf16_rne(vb.w - __uint_as_float(h << 16));
            }
            *(ushort4*)&sm.Bh[off] = h4;
            *(ushort4*)&sm.Bl[off] = l4;
        }
        __syncthreads();

        short8 ah[4], al[4], bh[4], bl[4];
        #pragma unroll
        for (int mm = 0; mm < 4; ++mm) {
            int row = wr*64 + mm*16 + lr;
            int off = row*32 + ((ls ^ ((row >> 1) & 3)) * 8);
            ah[mm] = *(const short8*)&sm.Ah[off];
            al[mm] = *(const short8*)&sm.Al[off];
        }
        #pragma unroll
        for (int nn = 0; nn < 4; ++nn) {
            int row = wc*64 + nn*16 + lr;
            int off = row*32 + ((ls ^ ((row >> 1) & 3)) * 8);
            bh[nn] = *(const short8*)&sm.Bh[off];
            bl[nn] = *(const short8*)&sm.Bl[off];
        }
        #pragma unroll
        for (int mm = 0; mm < 4; ++mm)
            #pragma unroll
            for (int nn = 0; nn < 4; ++nn) {
                acc[mm][nn] = __builtin_amdgcn_mfma_f32_16x16x32_bf16(ah[mm], bh[nn], acc[mm][nn], 0, 0, 0);
                acc[mm][nn] = __builtin_amdgcn_mfma_f32_16x16x32_bf16(ah[mm], bl[nn], acc[mm][nn], 0, 0, 0);
                acc[mm][nn] = __builtin_amdgcn_mfma_f32_16x16x32_bf16(al[mm], bh[nn], acc[mm][nn], 0, 0, 0);
            }
    }
}

// per-pair max row-norm^2 -> conservative |sim| bound R (Cauchy-Schwarz)
__global__ __launch_bounds__(256) void rownorm_kernel(
    const float* __restrict__ Xin, const float* __restrict__ Xtg, uint32_t* __restrict__ Ru)
{
    const int p = blockIdx.x;             // p = m*8 + b
    const int mm = p >> 3, b = p & 7;
    const float* X = (mm ? Xtg : Xin) + (size_t)b * N_ * D_;
    const int row = blockIdx.y * 256 + threadIdx.x;
    const float4* r4 = (const float4*)&X[(size_t)row * D_];
    float s = 0.f;
    #pragma unroll
    for (int i = 0; i < 32; ++i) {
        float4 v = r4[i];
        s += v.x*v.x + v.y*v.y + v.z*v.z + v.w*v.w;
    }
    #pragma unroll
    for (int off = 32; off; off >>= 1) s = fmaxf(s, __shfl_down(s, off));
    __shared__ float wm[4];
    const int t = threadIdx.x;
    if ((t & 63) == 0) wm[t >> 6] = s;
    __syncthreads();
    if (t == 0) {
        float mx = fmaxf(fmaxf(wm[0], wm[1]), fmaxf(wm[2], wm[3]));
        atomicMax(&Ru[p], __float_as_uint(mx));   // positive floats: uint order == float order
    }
}

// MODE 0: linear 1024-bin LDS hist -> weighted flush to global
// MODE 1: append fkey of values in selected bin (w copies) to per-pair list
// MODE 2: masked MSE over both matrices -> double atomic
template<int MODE>
__global__ __launch_bounds__(256) void sim_kernel(
    const float* __restrict__ Xin, const float* __restrict__ Xtg,
    const uint32_t* __restrict__ Ru, uint32_t* __restrict__ hist,
    const uint32_t* __restrict__ sel, uint32_t* __restrict__ cnts,
    uint32_t* __restrict__ lists,
    const float* __restrict__ thr, double* __restrict__ accum)
{
    __shared__ Panels sm;
    __shared__ uint32_t lh[(MODE == 0) ? NBIN : 1];

    const int t = threadIdx.x;
    const int b = blockIdx.y;
    const int mz = (MODE == 2) ? 0 : blockIdx.z;

    if (MODE == 0)
        for (int i = t; i < NBIN; i += 256) lh[i] = 0;
    // ordered vs atomics by compute_tile's first __syncthreads

    int rem = blockIdx.x, ti = 0;
    while (true) { int len = NT - ti; if (rem < len) break; rem -= len; ++ti; }
    const int tj = ti + rem;
    const uint32_t w = (ti == tj) ? 1u : 2u;

    const float* X = (mz ? Xtg : Xin) + (size_t)b * N_ * D_;
    f32x4 acc[4][4];
    compute_tile(X, ti, tj, sm, acc, t);

    if (MODE == 0) {
        const int p = mz * B_ + b;
        const float R = __uint_as_float(Ru[p]);
        const float scl = (float)NBIN / (2.0f * R);
        #pragma unroll
        for (int mm = 0; mm < 4; ++mm)
            #pragma unroll
            for (int nn = 0; nn < 4; ++nn)
                #pragma unroll
                for (int r = 0; r < 4; ++r)
                    atomicAdd(&lh[binof(acc[mm][nn][r], R, scl)], 1u);
        __syncthreads();
        uint32_t* gh = hist + (size_t)p * NBIN;
        for (int i = t; i < NBIN; i += 256) {
            uint32_t c = lh[i];
            if (c) atomicAdd(&gh[i], c * w);
        }
    } else if (MODE == 1) {
        const int p = mz * B_ + b;
        const float R = __uint_as_float(Ru[p]);
        const float scl = (float)NBIN / (2.0f * R);
        const int s = (int)sel[p];
        uint32_t* list = lists + (size_t)p * CAP;
        #pragma unroll
        for (int mm = 0; mm < 4; ++mm)
            #pragma unroll
            for (int nn = 0; nn < 4; ++nn)
                #pragma unroll
                for (int r = 0; r < 4; ++r) {
                    float v = acc[mm][nn][r];
                    if (binof(v, R, scl) == s) {
                        uint32_t key = fkey(v);
                        uint32_t idx = atomicAdd(&cnts[p], w);
                        for (uint32_t j = 0; j < w; ++j)
                            if (idx + j < CAP) list[idx + j] = key;
                    }
                }
    } else {
        f32x4 accT[4][4];
        compute_tile(Xtg + (size_t)b * N_ * D_, ti, tj, sm, accT, t);
        const float thrI = thr[b], thrT = thr[B_ + b];
        float local = 0.f;
        #pragma unroll
        for (int mm = 0; mm < 4; ++mm)
            #pragma unroll
            for (int nn = 0; nn < 4; ++nn)
                #pragma unroll
                for (int r = 0; r < 4; ++r) {
                    float vI = acc[mm][nn][r],  aI = (vI >= thrI) ? vI : 0.f;
                    float vT = accT[mm][nn][r], aT = (vT >= thrT) ? vT : 0.f;
                    float d = aI - aT;
                    local += d * d;
                }
        local *= (float)w;
        #pragma unroll
        for (int off = 32; off; off >>= 1) local += __shfl_down(local, off);
        __shared__ float wsum[4];
        if ((t & 63) == 0) wsum[t >> 6] = local;
        __syncthreads();
        if (t == 0) {
            double s2 = (double)wsum[0] + (double)wsum[1] + (double)wsum[2] + (double)wsum[3];
            atomicAdd(accum, s2);
        }
    }
}

// find bin containing k-th largest (descending scan), output bracket + remaining rank
__global__ __launch_bounds__(256) void select1(
    const uint32_t* __restrict__ hist, const int* __restrict__ kptr,
    uint32_t* __restrict__ sel, uint32_t* __restrict__ krem)
{
    const int p = blockIdx.x, t = threadIdx.x;
    const uint32_t* h = hist + (size_t)p * NBIN;
    const uint32_t k0 = (uint32_t)kptr[0];
    __shared__ uint32_t csum[256], cpre[256];
    const int top = NBIN - 1 - t * 4;
    uint32_t s = 0;
    #pragma unroll
    for (int j = 0; j < 4; ++j) s += h[top - j];
    csum[t] = s;
    __syncthreads();
    if (t == 0) { uint32_t run = 0; for (int i = 0; i < 256; ++i) { cpre[i] = run; run += csum[i]; } }
    __syncthreads();
    const uint32_t above = cpre[t];
    if (above < k0 && above + s >= k0) {
        uint32_t cum = above;
        for (int j = 0; j < 4; ++j) {
            int bin = top - j;
            uint32_t c = h[bin];
            cum += c;
            if (cum >= k0) { sel[p] = (uint32_t)bin; krem[p] = k0 - (cum - c); break; }
        }
    }
}

// exact k-th largest within appended list: 4-round byte radix on monotonic keys
__global__ __launch_bounds__(256) void select2(
    const uint32_t* __restrict__ lists, const uint32_t* __restrict__ cnts,
    const uint32_t* __restrict__ kremIn, float* __restrict__ thr)
{
    const int p = blockIdx.x, t = threadIdx.x;
    const uint32_t* list = lists + (size_t)p * CAP;
    const uint32_t n = min(cnts[p], (uint32_t)CAP);
    __shared__ uint32_t h[256];
    __shared__ uint32_t spref, skrem;
    if (t == 0) { spref = 0; skrem = kremIn[p]; }
    uint32_t mask = 0;
    __syncthreads();
    for (int round = 0; round < 4; ++round) {
        const int shift = 24 - 8 * round;
        h[t] = 0;
        __syncthreads();
        const uint32_t pref = spref;
        for (uint32_t i = t; i < n; i += 256) {
            uint32_t key = list[i];
            if ((key & mask) == pref) atomicAdd(&h[(key >> shift) & 255u], 1u);
        }
        __syncthreads();
        if (t == 0) {
            uint32_t kr = skrem, acc2 = 0;
            for (int b2 = 255; b2 >= 0; --b2) {
                uint32_t c = h[b2];
                if (acc2 + c >= kr) { skrem = kr - acc2; spref = pref | ((uint32_t)b2 << shift); break; }
                acc2 += c;
            }
        }
        __syncthreads();
        mask |= 0xFFu << shift;
    }
    if (t == 0) thr[p] = keyf(spref);
}

__global__ void finalize_kernel(const double* __restrict__ accum, float* __restrict__ out) {
    out[0] = (float)(accum[0] / ((double)B_ * (double)N_ * (double)N_));
}

extern "C" void kernel_launch(void* const* d_in, const int* in_sizes, int n_in,
                              void* d_out, int out_size, void* d_ws, size_t ws_size,
                              hipStream_t stream)
{
    const float* Xin = (const float*)d_in[0];
    const float* Xtg = (const float*)d_in[1];
    const int*  kptr = (const int*)d_in[3];
    float* out = (float*)d_out;

    char* ws = (char*)d_ws;
    double*   accum = (double*)ws;                    // 8 B
    uint32_t* Ru    = (uint32_t*)(ws + 64);           // 16
    uint32_t* sel   = (uint32_t*)(ws + 128);          // 16
    uint32_t* krem  = (uint32_t*)(ws + 192);          // 16
    float*    thr   = (float*)   (ws + 256);          // 16
    uint32_t* cnts  = (uint32_t*)(ws + 320);          // 16
    uint32_t* hist  = (uint32_t*)(ws + 512);          // 16*1024*4 = 64 KB
    uint32_t* lists = (uint32_t*)(ws + 512 + 16*NBIN*4);
    const size_t need = 512 + (size_t)16*NBIN*4 + (size_t)16*CAP*4;
    if (ws_size < need) return;

    hipMemsetAsync(d_ws, 0, 512 + (size_t)16*NBIN*4, stream);  // accum,Ru,sel,krem,thr,cnts,hist

    dim3 blk(256);
    rownorm_kernel<<<dim3(16, 8), blk, 0, stream>>>(Xin, Xtg, Ru);
    sim_kernel<0><<<dim3(NPAIRS, B_, 2), blk, 0, stream>>>(Xin, Xtg, Ru, hist, sel, cnts, lists, thr, accum);
    select1<<<dim3(16), blk, 0, stream>>>(hist, kptr, sel, krem);
    sim_kernel<1><<<dim3(NPAIRS, B_, 2), blk, 0, stream>>>(Xin, Xtg, Ru, hist, sel, cnts, lists, thr, accum);
    select2<<<dim3(16), blk, 0, stream>>>(lists, cnts, krem, thr);
    sim_kernel<2><<<dim3(NPAIRS, B_, 1), blk, 0, stream>>>(Xin, Xtg, Ru, hist, sel, cnts, lists, thr, accum);
    finalize_kernel<<<1, 1, 0, stream>>>(accum, out);
}

// Round 3
// 290.639 us; speedup vs baseline: 7.6657x; 7.6657x over previous
//
#include <hip/hip_runtime.h>
#include <stdint.h>

#define N_ 2048
#define D_ 128
#define B_ 8
#define BT 128           // block tile
#define NT 16            // N_/BT
#define NPAIRS 136       // NT*(NT+1)/2 upper-triangle tile pairs
#define NBIN 1024
#define CAP 65536        // per-pair append capacity (expected ~24K)
#define LCAP 2048        // per-block LDS append buffer (expected ~184)

typedef __attribute__((ext_vector_type(8))) short short8;
typedef __attribute__((ext_vector_type(4))) float f32x4;

// ws layout (bytes)
#define OFF_ACCUM 0
#define OFF_RU    64
#define OFF_SEL   128
#define OFF_KREM  192
#define OFF_THR   256
#define OFF_CNTS  512                       // 16 counters padded 64 u32 apart (4 KB)
#define OFF_HIST  8192                      // 16*1024*4 = 64 KB
#define OFF_LISTS 73728                     // 16*65536*4 = 4 MB
#define OFF_H     4268032                   // 2*8*2048*128*2 = 8 MB
#define OFF_L     12656640                  // 8 MB
#define NEED_SMALL ((size_t)4268032)
#define NEED_BIG   ((size_t)21045248)

// monotonic key: ascending uint order == ascending float order
__device__ __forceinline__ uint32_t fkey(float f) {
    uint32_t u = __float_as_uint(f);
    return (u & 0x80000000u) ? ~u : (u | 0x80000000u);
}
__device__ __forceinline__ float keyf(uint32_t k) {
    uint32_t u = (k & 0x80000000u) ? (k & 0x7fffffffu) : ~k;
    return __uint_as_float(u);
}
// f32 -> bf16 bits, round-to-nearest-even (finite inputs only)
__device__ __forceinline__ uint32_t bf16_rne(float x) {
    uint32_t u = __float_as_uint(x);
    return (u + 0x7fffu + ((u >> 16) & 1u)) >> 16;
}
// linear bin — identical expression in hist and append passes
__device__ __forceinline__ int binof(float v, float R, float scl) {
    int b = (int)((v + R) * scl);
    if (b < 0) b = 0;
    if (b >= NBIN) b = NBIN - 1;
    return b;
}

struct Panels { ushort Ah[BT*32], Al[BT*32], Bh[BT*32], Bl[BT*32]; }; // 32 KB

// 128x128 tile (ti,tj) of Xb*Xb^T via split-bf16 MFMA (hi*hi + hi*lo + lo*hi).
// 4 waves (2x2), each wave 64x64 = 4x4 frags of 16x16x32.
// LDS [row][32k] bf16, 16B-slot swizzle slot' = slot ^ ((row>>1)&3).
template<bool PRE>
__device__ __forceinline__ void compute_tile(const float* __restrict__ Xb,
        const ushort* __restrict__ Hb, const ushort* __restrict__ Lb,
        int ti, int tj, Panels& sm, f32x4 acc[4][4], int t)
{
    const int lane = t & 63;
    const int wv = t >> 6;
    const int wr = wv >> 1, wc = wv & 1;
    const int lr = lane & 15;
    const int ls = lane >> 4;

    #pragma unroll
    for (int mm = 0; mm < 4; ++mm)
        #pragma unroll
        for (int nn = 0; nn < 4; ++nn)
            acc[mm][nn] = f32x4{0.f, 0.f, 0.f, 0.f};

    for (int kc = 0; kc < D_; kc += 32) {
        __syncthreads();   // also orders pre-loop LDS init vs first writes
        if (PRE) {
            #pragma unroll
            for (int j = 0; j < 2; ++j) {
                int q = t + 256*j;            // 0..511 -> 128 rows x 4 groups
                int row = q >> 2, g = q & 3;
                int off = row*32 + ((g ^ ((row >> 1) & 3)) * 8);
                size_t ga = (size_t)(ti*BT + row)*D_ + kc + g*8;
                size_t gb = (size_t)(tj*BT + row)*D_ + kc + g*8;
                *(short8*)&sm.Ah[off] = *(const short8*)&Hb[ga];
                *(short8*)&sm.Al[off] = *(const short8*)&Lb[ga];
                *(short8*)&sm.Bh[off] = *(const short8*)&Hb[gb];
                *(short8*)&sm.Bl[off] = *(const short8*)&Lb[gb];
            }
        } else {
            #pragma unroll
            for (int i = 0; i < 4; ++i) {
                int q = t + 256*i;
                int row = q >> 3, f4 = q & 7;
                float4 va = *(const float4*)&Xb[(size_t)(ti*BT + row)*D_ + kc + f4*4];
                float4 vb = *(const float4*)&Xb[(size_t)(tj*BT + row)*D_ + kc + f4*4];
                int sp  = (f4 >> 1) ^ ((row >> 1) & 3);
                int off = row*32 + sp*8 + (f4 & 1)*4;
                ushort4 h4, l4;
                uint32_t h;
                h = bf16_rne(va.x); h4.x = (ushort)h; l4.x = (ushort)bf16_rne(va.x - __uint_as_float(h << 16));
                h = bf16_rne(va.y); h4.y = (ushort)h; l4.y = (ushort)bf16_rne(va.y - __uint_as_float(h << 16));
                h = bf16_rne(va.z); h4.z = (ushort)h; l4.z = (ushort)bf16_rne(va.z - __uint_as_float(h << 16));
                h = bf16_rne(va.w); h4.w = (ushort)h; l4.w = (ushort)bf16_rne(va.w - __uint_as_float(h << 16));
                *(ushort4*)&sm.Ah[off] = h4;
                *(ushort4*)&sm.Al[off] = l4;
                h = bf16_rne(vb.x); h4.x = (ushort)h; l4.x = (ushort)bf16_rne(vb.x - __uint_as_float(h << 16));
                h = bf16_rne(vb.y); h4.y = (ushort)h; l4.y = (ushort)bf16_rne(vb.y - __uint_as_float(h << 16));
                h = bf16_rne(vb.z); h4.z = (ushort)h; l4.z = (ushort)bf16_rne(vb.z - __uint_as_float(h << 16));
                h = bf16_rne(vb.w); h4.w = (ushort)h; l4.w = (ushort)bf16_rne(vb.w - __uint_as_float(h << 16));
                *(ushort4*)&sm.Bh[off] = h4;
                *(ushort4*)&sm.Bl[off] = l4;
            }
        }
        __syncthreads();

        short8 ah[4], al[4], bh[4], bl[4];
        #pragma unroll
        for (int mm = 0; mm < 4; ++mm) {
            int row = wr*64 + mm*16 + lr;
            int off = row*32 + ((ls ^ ((row >> 1) & 3)) * 8);
            ah[mm] = *(const short8*)&sm.Ah[off];
            al[mm] = *(const short8*)&sm.Al[off];
        }
        #pragma unroll
        for (int nn = 0; nn < 4; ++nn) {
            int row = wc*64 + nn*16 + lr;
            int off = row*32 + ((ls ^ ((row >> 1) & 3)) * 8);
            bh[nn] = *(const short8*)&sm.Bh[off];
            bl[nn] = *(const short8*)&sm.Bl[off];
        }
        #pragma unroll
        for (int mm = 0; mm < 4; ++mm)
            #pragma unroll
            for (int nn = 0; nn < 4; ++nn) {
                acc[mm][nn] = __builtin_amdgcn_mfma_f32_16x16x32_bf16(ah[mm], bh[nn], acc[mm][nn], 0, 0, 0);
                acc[mm][nn] = __builtin_amdgcn_mfma_f32_16x16x32_bf16(ah[mm], bl[nn], acc[mm][nn], 0, 0, 0);
                acc[mm][nn] = __builtin_amdgcn_mfma_f32_16x16x32_bf16(al[mm], bh[nn], acc[mm][nn], 0, 0, 0);
            }
    }
}

// f32 -> (hi,lo) bf16 planes, one shot
__global__ __launch_bounds__(256) void convert_kernel(
    const float* __restrict__ Xin, const float* __restrict__ Xtg,
    ushort* __restrict__ H, ushort* __restrict__ L)
{
    const size_t i = ((size_t)blockIdx.x * 256 + threadIdx.x) * 8;  // element idx within matrix
    const float* X = blockIdx.y ? Xtg : Xin;
    const size_t base = (size_t)blockIdx.y * (size_t)B_ * N_ * D_;
    float4 v0 = *(const float4*)&X[i];
    float4 v1 = *(const float4*)&X[i + 4];
    ushort h8[8], l8[8];
    float vv[8] = {v0.x, v0.y, v0.z, v0.w, v1.x, v1.y, v1.z, v1.w};
    #pragma unroll
    for (int j = 0; j < 8; ++j) {
        uint32_t h = bf16_rne(vv[j]);
        h8[j] = (ushort)h;
        l8[j] = (ushort)bf16_rne(vv[j] - __uint_as_float(h << 16));
    }
    *(short8*)&H[base + i] = *(short8*)h8;
    *(short8*)&L[base + i] = *(short8*)l8;
}

// per-pair max row-norm^2 -> conservative |sim| bound R (Cauchy-Schwarz)
__global__ __launch_bounds__(256) void rownorm_kernel(
    const float* __restrict__ Xin, const float* __restrict__ Xtg, uint32_t* __restrict__ Ru)
{
    const int p = blockIdx.x;             // p = m*8 + b
    const int mm = p >> 3, b = p & 7;
    const float* X = (mm ? Xtg : Xin) + (size_t)b * N_ * D_;
    const int row = blockIdx.y * 256 + threadIdx.x;
    const float4* r4 = (const float4*)&X[(size_t)row * D_];
    float s = 0.f;
    #pragma unroll
    for (int i = 0; i < 32; ++i) {
        float4 v = r4[i];
        s += v.x*v.x + v.y*v.y + v.z*v.z + v.w*v.w;
    }
    #pragma unroll
    for (int off = 32; off; off >>= 1) s = fmaxf(s, __shfl_down(s, off));
    __shared__ float wm[4];
    const int t = threadIdx.x;
    if ((t & 63) == 0) wm[t >> 6] = s;
    __syncthreads();
    if (t == 0) {
        float mx = fmaxf(fmaxf(wm[0], wm[1]), fmaxf(wm[2], wm[3]));
        atomicMax(&Ru[p], __float_as_uint(mx));
    }
}

// MODE 0: linear 1024-bin LDS hist -> weighted flush
// MODE 1: append keys in selected bin, LDS-buffered, one global atomic per block
// MODE 2: masked MSE over both matrices -> double atomic
template<int MODE, bool PRE>
__global__ __launch_bounds__(256) void sim_kernel(
    const float* __restrict__ Xin, const float* __restrict__ Xtg,
    const ushort* __restrict__ H, const ushort* __restrict__ L,
    const uint32_t* __restrict__ Ru, uint32_t* __restrict__ hist,
    const uint32_t* __restrict__ sel, uint32_t* __restrict__ cnts,
    uint32_t* __restrict__ lists,
    const float* __restrict__ thr, double* __restrict__ accum)
{
    __shared__ Panels sm;
    __shared__ uint32_t lh[(MODE == 0) ? NBIN : 1];
    __shared__ uint32_t lbuf[(MODE == 1) ? LCAP : 1];
    __shared__ uint32_t slcnt, sbase;

    const int t = threadIdx.x;
    const int b = blockIdx.y;
    const int mz = (MODE == 2) ? 0 : blockIdx.z;

    if (MODE == 0)
        for (int i = t; i < NBIN; i += 256) lh[i] = 0;
    if (MODE == 1 && t == 0) slcnt = 0;
    // ordered vs later use by compute_tile's first __syncthreads

    int rem = blockIdx.x, ti = 0;
    while (true) { int len = NT - ti; if (rem < len) break; rem -= len; ++ti; }
    const int tj = ti + rem;
    const uint32_t w = (ti == tj) ? 1u : 2u;

    const int p = mz * B_ + b;
    const float* X = (mz ? Xtg : Xin) + (size_t)b * N_ * D_;
    const ushort* Hb = PRE ? H + (size_t)p * N_ * D_ : nullptr;
    const ushort* Lb = PRE ? L + (size_t)p * N_ * D_ : nullptr;

    f32x4 acc[4][4];
    compute_tile<PRE>(X, Hb, Lb, ti, tj, sm, acc, t);

    if (MODE == 0) {
        const float R = __uint_as_float(Ru[p]);
        const float scl = (float)NBIN / (2.0f * R);
        #pragma unroll
        for (int mm = 0; mm < 4; ++mm)
            #pragma unroll
            for (int nn = 0; nn < 4; ++nn)
                #pragma unroll
                for (int r = 0; r < 4; ++r)
                    atomicAdd(&lh[binof(acc[mm][nn][r], R, scl)], 1u);
        __syncthreads();
        uint32_t* gh = hist + (size_t)p * NBIN;
        for (int i = t; i < NBIN; i += 256) {
            uint32_t c = lh[i];
            if (c) atomicAdd(&gh[i], c * w);
        }
    } else if (MODE == 1) {
        const float R = __uint_as_float(Ru[p]);
        const float scl = (float)NBIN / (2.0f * R);
        const int s = (int)sel[p];
        uint32_t* list = lists + (size_t)p * CAP;
        uint32_t* gcnt = &cnts[p * 64];
        #pragma unroll
        for (int mm = 0; mm < 4; ++mm)
            #pragma unroll
            for (int nn = 0; nn < 4; ++nn)
                #pragma unroll
                for (int r = 0; r < 4; ++r) {
                    float v = acc[mm][nn][r];
                    if (binof(v, R, scl) == s) {
                        uint32_t key = fkey(v);
                        for (uint32_t j = 0; j < w; ++j) {
                            uint32_t idx = atomicAdd(&slcnt, 1u);
                            if (idx < LCAP) lbuf[idx] = key;
                            else { uint32_t g = atomicAdd(gcnt, 1u); if (g < CAP) list[g] = key; }
                        }
                    }
                }
        __syncthreads();
        const uint32_t m = min(slcnt, (uint32_t)LCAP);
        if (t == 0) sbase = atomicAdd(gcnt, m);
        __syncthreads();
        const uint32_t base = sbase;
        for (uint32_t i = t; i < m; i += 256) {
            uint32_t idx = base + i;
            if (idx < CAP) list[idx] = lbuf[i];
        }
    } else {
        f32x4 accT[4][4];
        const ushort* HbT = PRE ? H + (size_t)(B_ + b) * N_ * D_ : nullptr;
        const ushort* LbT = PRE ? L + (size_t)(B_ + b) * N_ * D_ : nullptr;
        compute_tile<PRE>(Xtg + (size_t)b * N_ * D_, HbT, LbT, ti, tj, sm, accT, t);
        const float thrI = thr[b], thrT = thr[B_ + b];
        float local = 0.f;
        #pragma unroll
        for (int mm = 0; mm < 4; ++mm)
            #pragma unroll
            for (int nn = 0; nn < 4; ++nn)
                #pragma unroll
                for (int r = 0; r < 4; ++r) {
                    float vI = acc[mm][nn][r],  aI = (vI >= thrI) ? vI : 0.f;
                    float vT = accT[mm][nn][r], aT = (vT >= thrT) ? vT : 0.f;
                    float d = aI - aT;
                    local += d * d;
                }
        local *= (float)w;
        #pragma unroll
        for (int off = 32; off; off >>= 1) local += __shfl_down(local, off);
        __shared__ float wsum[4];
        if ((t & 63) == 0) wsum[t >> 6] = local;
        __syncthreads();
        if (t == 0) {
            double s2 = (double)wsum[0] + (double)wsum[1] + (double)wsum[2] + (double)wsum[3];
            atomicAdd(accum, s2);
        }
    }
}

__global__ __launch_bounds__(256) void select1(
    const uint32_t* __restrict__ hist, const int* __restrict__ kptr,
    uint32_t* __restrict__ sel, uint32_t* __restrict__ krem)
{
    const int p = blockIdx.x, t = threadIdx.x;
    const uint32_t* h = hist + (size_t)p * NBIN;
    const uint32_t k0 = (uint32_t)kptr[0];
    __shared__ uint32_t csum[256], cpre[256];
    const int top = NBIN - 1 - t * 4;
    uint32_t s = 0;
    #pragma unroll
    for (int j = 0; j < 4; ++j) s += h[top - j];
    csum[t] = s;
    __syncthreads();
    if (t == 0) { uint32_t run = 0; for (int i = 0; i < 256; ++i) { cpre[i] = run; run += csum[i]; } }
    __syncthreads();
    const uint32_t above = cpre[t];
    if (above < k0 && above + s >= k0) {
        uint32_t cum = above;
        for (int j = 0; j < 4; ++j) {
            int bin = top - j;
            uint32_t c = h[bin];
            cum += c;
            if (cum >= k0) { sel[p] = (uint32_t)bin; krem[p] = k0 - (cum - c); break; }
        }
    }
}

// exact k-th largest within appended list: 4-round byte radix on monotonic keys
__global__ __launch_bounds__(256) void select2(
    const uint32_t* __restrict__ lists, const uint32_t* __restrict__ cnts,
    const uint32_t* __restrict__ kremIn, float* __restrict__ thr)
{
    const int p = blockIdx.x, t = threadIdx.x;
    const uint32_t* list = lists + (size_t)p * CAP;
    const uint32_t n = min(cnts[p * 64], (uint32_t)CAP);
    __shared__ uint32_t h[256];
    __shared__ uint32_t spref, skrem;
    if (t == 0) { spref = 0; skrem = kremIn[p]; }
    uint32_t mask = 0;
    __syncthreads();
    for (int round = 0; round < 4; ++round) {
        const int shift = 24 - 8 * round;
        h[t] = 0;
        __syncthreads();
        const uint32_t pref = spref;
        for (uint32_t i = t; i < n; i += 256) {
            uint32_t key = list[i];
            if ((key & mask) == pref) atomicAdd(&h[(key >> shift) & 255u], 1u);
        }
        __syncthreads();
        if (t == 0) {
            uint32_t kr = skrem, acc2 = 0;
            for (int b2 = 255; b2 >= 0; --b2) {
                uint32_t c = h[b2];
                if (acc2 + c >= kr) { skrem = kr - acc2; spref = pref | ((uint32_t)b2 << shift); break; }
                acc2 += c;
            }
        }
        __syncthreads();
        mask |= 0xFFu << shift;
    }
    if (t == 0) thr[p] = keyf(spref);
}

__global__ void finalize_kernel(const double* __restrict__ accum, float* __restrict__ out) {
    out[0] = (float)(accum[0] / ((double)B_ * (double)N_ * (double)N_));
}

extern "C" void kernel_launch(void* const* d_in, const int* in_sizes, int n_in,
                              void* d_out, int out_size, void* d_ws, size_t ws_size,
                              hipStream_t stream)
{
    const float* Xin = (const float*)d_in[0];
    const float* Xtg = (const float*)d_in[1];
    const int*  kptr = (const int*)d_in[3];
    float* out = (float*)d_out;

    char* ws = (char*)d_ws;
    double*   accum = (double*)  (ws + OFF_ACCUM);
    uint32_t* Ru    = (uint32_t*)(ws + OFF_RU);
    uint32_t* sel   = (uint32_t*)(ws + OFF_SEL);
    uint32_t* krem  = (uint32_t*)(ws + OFF_KREM);
    float*    thr   = (float*)   (ws + OFF_THR);
    uint32_t* cnts  = (uint32_t*)(ws + OFF_CNTS);
    uint32_t* hist  = (uint32_t*)(ws + OFF_HIST);
    uint32_t* lists = (uint32_t*)(ws + OFF_LISTS);
    ushort*   H     = (ushort*)  (ws + OFF_H);
    ushort*   L     = (ushort*)  (ws + OFF_L);
    if (ws_size < NEED_SMALL) return;
    const bool pre = (ws_size >= NEED_BIG);

    // zero accum,Ru,sel,krem,thr,cnts,hist (lists need no init)
    hipMemsetAsync(d_ws, 0, OFF_HIST + (size_t)16 * NBIN * 4, stream);

    dim3 blk(256);
    if (pre)
        convert_kernel<<<dim3(1024, 2), blk, 0, stream>>>(Xin, Xtg, H, L);
    rownorm_kernel<<<dim3(16, 8), blk, 0, stream>>>(Xin, Xtg, Ru);
    if (pre) {
        sim_kernel<0, true><<<dim3(NPAIRS, B_, 2), blk, 0, stream>>>(Xin, Xtg, H, L, Ru, hist, sel, cnts, lists, thr, accum);
        select1<<<dim3(16), blk, 0, stream>>>(hist, kptr, sel, krem);
        sim_kernel<1, true><<<dim3(NPAIRS, B_, 2), blk, 0, stream>>>(Xin, Xtg, H, L, Ru, hist, sel, cnts, lists, thr, accum);
        select2<<<dim3(16), blk, 0, stream>>>(lists, cnts, krem, thr);
        sim_kernel<2, true><<<dim3(NPAIRS, B_, 1), blk, 0, stream>>>(Xin, Xtg, H, L, Ru, hist, sel, cnts, lists, thr, accum);
    } else {
        sim_kernel<0, false><<<dim3(NPAIRS, B_, 2), blk, 0, stream>>>(Xin, Xtg, H, L, Ru, hist, sel, cnts, lists, thr, accum);
        select1<<<dim3(16), blk, 0, stream>>>(hist, kptr, sel, krem);
        sim_kernel<1, false><<<dim3(NPAIRS, B_, 2), blk, 0, stream>>>(Xin, Xtg, H, L, Ru, hist, sel, cnts, lists, thr, accum);
        select2<<<dim3(16), blk, 0, stream>>>(lists, cnts, krem, thr);
        sim_kernel<2, false><<<dim3(NPAIRS, B_, 1), blk, 0, stream>>>(Xin, Xtg, H, L, Ru, hist, sel, cnts, lists, thr, accum);
    }
    finalize_kernel<<<1, 1, 0, stream>>>(accum, out);
}

// Round 4
// 177.759 us; speedup vs baseline: 12.5334x; 1.6350x over previous
//
#include <hip/hip_runtime.h>
#include <stdint.h>

#define N_ 2048
#define D_ 128
#define B_ 8
#define BT 128           // block tile
#define NT 16            // N_/BT
#define NPAIRS 136       // NT*(NT+1)/2 upper-triangle tile pairs
#define NBIN 1024

typedef __attribute__((ext_vector_type(8))) short short8;
typedef __attribute__((ext_vector_type(4))) float f32x4;

// ws layout (bytes)
#define OFF_ACCUM 0
#define OFF_RU    64
#define OFF_SEL   128
#define OFF_KREM  192
#define OFF_THR   256
#define OFF_HIST  512                        // 16*1024*4 = 64 KB  (coarse)
#define OFF_HIST2 (512 + 16*NBIN*4)          // 16*1024*4 = 64 KB  (refinement)
#define OFF_END   (512 + 32*NBIN*4)          // 131584 (256-aligned)
#define OFF_H     ((size_t)OFF_END)          // 2 matrices * 8*2048*128 * 2B = 8 MB
#define OFF_L     (OFF_H + (size_t)8388608)  // 8 MB
#define NEED_SMALL ((size_t)OFF_END)
#define NEED_BIG   (OFF_H + (size_t)16777216)

// f32 -> bf16 bits, round-to-nearest-even (finite inputs only)
__device__ __forceinline__ uint32_t bf16_rne(float x) {
    uint32_t u = __float_as_uint(x);
    return (u + 0x7fffu + ((u >> 16) & 1u)) >> 16;
}
// coarse linear bin — identical expression in MODE0 and MODE1
__device__ __forceinline__ int binof(float v, float R, float scl) {
    int b = (int)((v + R) * scl);
    if (b < 0) b = 0;
    if (b >= NBIN) b = NBIN - 1;
    return b;
}

struct Panels { ushort Ah[BT*32], Al[BT*32], Bh[BT*32], Bl[BT*32]; }; // 32 KB

// 128x128 tile (ti,tj) of Xb*Xb^T via split-bf16 MFMA (hi*hi + hi*lo + lo*hi).
// 4 waves (2x2), each wave 64x64 = 4x4 frags of 16x16x32.
// LDS [row][32k] bf16, 16B-slot swizzle slot' = slot ^ ((row>>1)&3).
template<bool PRE>
__device__ __forceinline__ void compute_tile(const float* __restrict__ Xb,
        const ushort* __restrict__ Hb, const ushort* __restrict__ Lb,
        int ti, int tj, Panels& sm, f32x4 acc[4][4], int t)
{
    const int lane = t & 63;
    const int wv = t >> 6;
    const int wr = wv >> 1, wc = wv & 1;
    const int lr = lane & 15;
    const int ls = lane >> 4;

    #pragma unroll
    for (int mm = 0; mm < 4; ++mm)
        #pragma unroll
        for (int nn = 0; nn < 4; ++nn)
            acc[mm][nn] = f32x4{0.f, 0.f, 0.f, 0.f};

    for (int kc = 0; kc < D_; kc += 32) {
        __syncthreads();   // also orders pre-loop LDS init vs first writes
        if (PRE) {
            #pragma unroll
            for (int j = 0; j < 2; ++j) {
                int q = t + 256*j;            // 0..511 -> 128 rows x 4 groups
                int row = q >> 2, g = q & 3;
                int off = row*32 + ((g ^ ((row >> 1) & 3)) * 8);
                size_t ga = (size_t)(ti*BT + row)*D_ + kc + g*8;
                size_t gb = (size_t)(tj*BT + row)*D_ + kc + g*8;
                *(short8*)&sm.Ah[off] = *(const short8*)&Hb[ga];
                *(short8*)&sm.Al[off] = *(const short8*)&Lb[ga];
                *(short8*)&sm.Bh[off] = *(const short8*)&Hb[gb];
                *(short8*)&sm.Bl[off] = *(const short8*)&Lb[gb];
            }
        } else {
            #pragma unroll
            for (int i = 0; i < 4; ++i) {
                int q = t + 256*i;
                int row = q >> 3, f4 = q & 7;
                float4 va = *(const float4*)&Xb[(size_t)(ti*BT + row)*D_ + kc + f4*4];
                float4 vb = *(const float4*)&Xb[(size_t)(tj*BT + row)*D_ + kc + f4*4];
                int sp  = (f4 >> 1) ^ ((row >> 1) & 3);
                int off = row*32 + sp*8 + (f4 & 1)*4;
                ushort4 h4, l4;
                uint32_t h;
                h = bf16_rne(va.x); h4.x = (ushort)h; l4.x = (ushort)bf16_rne(va.x - __uint_as_float(h << 16));
                h = bf16_rne(va.y); h4.y = (ushort)h; l4.y = (ushort)bf16_rne(va.y - __uint_as_float(h << 16));
                h = bf16_rne(va.z); h4.z = (ushort)h; l4.z = (ushort)bf16_rne(va.z - __uint_as_float(h << 16));
                h = bf16_rne(va.w); h4.w = (ushort)h; l4.w = (ushort)bf16_rne(va.w - __uint_as_float(h << 16));
                *(ushort4*)&sm.Ah[off] = h4;
                *(ushort4*)&sm.Al[off] = l4;
                h = bf16_rne(vb.x); h4.x = (ushort)h; l4.x = (ushort)bf16_rne(vb.x - __uint_as_float(h << 16));
                h = bf16_rne(vb.y); h4.y = (ushort)h; l4.y = (ushort)bf16_rne(vb.y - __uint_as_float(h << 16));
                h = bf16_rne(vb.z); h4.z = (ushort)h; l4.z = (ushort)bf16_rne(vb.z - __uint_as_float(h << 16));
                h = bf16_rne(vb.w); h4.w = (ushort)h; l4.w = (ushort)bf16_rne(vb.w - __uint_as_float(h << 16));
                *(ushort4*)&sm.Bh[off] = h4;
                *(ushort4*)&sm.Bl[off] = l4;
            }
        }
        __syncthreads();

        short8 ah[4], al[4], bh[4], bl[4];
        #pragma unroll
        for (int mm = 0; mm < 4; ++mm) {
            int row = wr*64 + mm*16 + lr;
            int off = row*32 + ((ls ^ ((row >> 1) & 3)) * 8);
            ah[mm] = *(const short8*)&sm.Ah[off];
            al[mm] = *(const short8*)&sm.Al[off];
        }
        #pragma unroll
        for (int nn = 0; nn < 4; ++nn) {
            int row = wc*64 + nn*16 + lr;
            int off = row*32 + ((ls ^ ((row >> 1) & 3)) * 8);
            bh[nn] = *(const short8*)&sm.Bh[off];
            bl[nn] = *(const short8*)&sm.Bl[off];
        }
        #pragma unroll
        for (int mm = 0; mm < 4; ++mm)
            #pragma unroll
            for (int nn = 0; nn < 4; ++nn) {
                acc[mm][nn] = __builtin_amdgcn_mfma_f32_16x16x32_bf16(ah[mm], bh[nn], acc[mm][nn], 0, 0, 0);
                acc[mm][nn] = __builtin_amdgcn_mfma_f32_16x16x32_bf16(ah[mm], bl[nn], acc[mm][nn], 0, 0, 0);
                acc[mm][nn] = __builtin_amdgcn_mfma_f32_16x16x32_bf16(al[mm], bh[nn], acc[mm][nn], 0, 0, 0);
            }
    }
}

// f32 -> (hi,lo) bf16 planes + fused per-pair max row-norm^2 (|sim| bound, CS)
__global__ __launch_bounds__(256) void convert_kernel(
    const float* __restrict__ Xin, const float* __restrict__ Xtg,
    ushort* __restrict__ H, ushort* __restrict__ L, uint32_t* __restrict__ Ru)
{
    const int t = threadIdx.x;
    const int m = blockIdx.y;
    const size_t i = ((size_t)blockIdx.x * 256 + t) * 8;   // block = 2048 elems = 16 rows, one b
    const float* X = m ? Xtg : Xin;
    const size_t base = (size_t)m * (size_t)B_ * N_ * D_;
    float4 v0 = *(const float4*)&X[i];
    float4 v1 = *(const float4*)&X[i + 4];
    ushort h8[8], l8[8];
    float vv[8] = {v0.x, v0.y, v0.z, v0.w, v1.x, v1.y, v1.z, v1.w};
    float s = 0.f;
    #pragma unroll
    for (int j = 0; j < 8; ++j) {
        uint32_t h = bf16_rne(vv[j]);
        h8[j] = (ushort)h;
        l8[j] = (ushort)bf16_rne(vv[j] - __uint_as_float(h << 16));
        s += vv[j] * vv[j];
    }
    *(short8*)&H[base + i] = *(short8*)h8;
    *(short8*)&L[base + i] = *(short8*)l8;
    // row = 16 lanes; xor<16 butterfly stays within the 16-lane row group
    s += __shfl_xor(s, 1); s += __shfl_xor(s, 2); s += __shfl_xor(s, 4); s += __shfl_xor(s, 8);
    s = fmaxf(s, __shfl_xor(s, 16)); s = fmaxf(s, __shfl_xor(s, 32));   // wave max over 4 rows
    __shared__ float wm[4];
    if ((t & 63) == 0) wm[t >> 6] = s;
    __syncthreads();
    if (t == 0) {
        float mx = fmaxf(fmaxf(wm[0], wm[1]), fmaxf(wm[2], wm[3]));
        const int b = blockIdx.x >> 7;        // 128 blocks per batch item
        atomicMax(&Ru[m * B_ + b], __float_as_uint(mx));  // positive: uint order == float order
    }
}

// standalone rownorm for the non-PRE fallback path
__global__ __launch_bounds__(256) void rownorm_kernel(
    const float* __restrict__ Xin, const float* __restrict__ Xtg, uint32_t* __restrict__ Ru)
{
    const int p = blockIdx.x;             // p = m*8 + b
    const int mm = p >> 3, b = p & 7;
    const float* X = (mm ? Xtg : Xin) + (size_t)b * N_ * D_;
    const int row = blockIdx.y * 256 + threadIdx.x;
    const float4* r4 = (const float4*)&X[(size_t)row * D_];
    float s = 0.f;
    #pragma unroll
    for (int i = 0; i < 32; ++i) {
        float4 v = r4[i];
        s += v.x*v.x + v.y*v.y + v.z*v.z + v.w*v.w;
    }
    #pragma unroll
    for (int off = 32; off; off >>= 1) s = fmaxf(s, __shfl_down(s, off));
    __shared__ float wm[4];
    const int t = threadIdx.x;
    if ((t & 63) == 0) wm[t >> 6] = s;
    __syncthreads();
    if (t == 0) {
        float mx = fmaxf(fmaxf(wm[0], wm[1]), fmaxf(wm[2], wm[3]));
        atomicMax(&Ru[p], __float_as_uint(mx));
    }
}

// MODE 0: coarse linear 1024-bin LDS hist -> weighted flush to hist
// MODE 1: refinement 1024-bin hist over selected coarse bin's range -> hist2
// MODE 2: masked MSE over both matrices -> double atomic
template<int MODE, bool PRE>
__global__ __launch_bounds__(256) void sim_kernel(
    const float* __restrict__ Xin, const float* __restrict__ Xtg,
    const ushort* __restrict__ H, const ushort* __restrict__ L,
    const uint32_t* __restrict__ Ru, uint32_t* __restrict__ hist,
    uint32_t* __restrict__ hist2, const uint32_t* __restrict__ sel,
    const float* __restrict__ thr, double* __restrict__ accum)
{
    __shared__ Panels sm;
    __shared__ uint32_t lh[(MODE <= 1) ? NBIN : 1];

    const int t = threadIdx.x;
    const int b = blockIdx.y;
    const int mz = (MODE == 2) ? 0 : blockIdx.z;

    if (MODE <= 1)
        for (int i = t; i < NBIN; i += 256) lh[i] = 0;
    // ordered vs later use by compute_tile's first __syncthreads

    int rem = blockIdx.x, ti = 0;
    while (true) { int len = NT - ti; if (rem < len) break; rem -= len; ++ti; }
    const int tj = ti + rem;
    const uint32_t w = (ti == tj) ? 1u : 2u;

    const int p = mz * B_ + b;
    const float* X = (mz ? Xtg : Xin) + (size_t)b * N_ * D_;
    const ushort* Hb = PRE ? H + (size_t)p * N_ * D_ : nullptr;
    const ushort* Lb = PRE ? L + (size_t)p * N_ * D_ : nullptr;

    f32x4 acc[4][4];
    compute_tile<PRE>(X, Hb, Lb, ti, tj, sm, acc, t);

    if (MODE == 0) {
        const float R = __uint_as_float(Ru[p]);
        const float scl = (float)NBIN / (2.0f * R);
        #pragma unroll
        for (int mm = 0; mm < 4; ++mm)
            #pragma unroll
            for (int nn = 0; nn < 4; ++nn)
                #pragma unroll
                for (int r = 0; r < 4; ++r)
                    atomicAdd(&lh[binof(acc[mm][nn][r], R, scl)], 1u);
        __syncthreads();
        uint32_t* gh = hist + (size_t)p * NBIN;
        for (int i = t; i < NBIN; i += 256) {
            uint32_t c = lh[i];
            if (c) atomicAdd(&gh[i], c * w);
        }
    } else if (MODE == 1) {
        const float R = __uint_as_float(Ru[p]);
        const float scl = (float)NBIN / (2.0f * R);
        const float binw = 2.0f * R / (float)NBIN;
        const int s = (int)sel[p];
        const float lo = fmaf((float)s, binw, -R);
        const float scl2 = (float)NBIN / binw;
        #pragma unroll
        for (int mm = 0; mm < 4; ++mm)
            #pragma unroll
            for (int nn = 0; nn < 4; ++nn)
                #pragma unroll
                for (int r = 0; r < 4; ++r) {
                    float v = acc[mm][nn][r];
                    if (binof(v, R, scl) == s) {
                        int j = (int)((v - lo) * scl2);
                        if (j < 0) j = 0;
                        if (j >= NBIN) j = NBIN - 1;
                        atomicAdd(&lh[j], 1u);
                    }
                }
        __syncthreads();
        uint32_t* gh = hist2 + (size_t)p * NBIN;
        for (int i = t; i < NBIN; i += 256) {
            uint32_t c = lh[i];
            if (c) atomicAdd(&gh[i], c * w);
        }
    } else {
        f32x4 accT[4][4];
        const ushort* HbT = PRE ? H + (size_t)(B_ + b) * N_ * D_ : nullptr;
        const ushort* LbT = PRE ? L + (size_t)(B_ + b) * N_ * D_ : nullptr;
        compute_tile<PRE>(Xtg + (size_t)b * N_ * D_, HbT, LbT, ti, tj, sm, accT, t);
        const float thrI = thr[b], thrT = thr[B_ + b];
        float local = 0.f;
        #pragma unroll
        for (int mm = 0; mm < 4; ++mm)
            #pragma unroll
            for (int nn = 0; nn < 4; ++nn)
                #pragma unroll
                for (int r = 0; r < 4; ++r) {
                    float vI = acc[mm][nn][r],  aI = (vI >= thrI) ? vI : 0.f;
                    float vT = accT[mm][nn][r], aT = (vT >= thrT) ? vT : 0.f;
                    float d = aI - aT;
                    local += d * d;
                }
        local *= (float)w;
        #pragma unroll
        for (int off = 32; off; off >>= 1) local += __shfl_down(local, off);
        __shared__ float wsum[4];
        if ((t & 63) == 0) wsum[t >> 6] = local;
        __syncthreads();
        if (t == 0) {
            double s2 = (double)wsum[0] + (double)wsum[1] + (double)wsum[2] + (double)wsum[3];
            atomicAdd(accum, s2);
        }
    }
}

// descending scan of coarse hist: bracket bin + remaining rank within it
__global__ __launch_bounds__(256) void select1(
    const uint32_t* __restrict__ hist, const int* __restrict__ kptr,
    uint32_t* __restrict__ sel, uint32_t* __restrict__ krem)
{
    const int p = blockIdx.x, t = threadIdx.x;
    const uint32_t* h = hist + (size_t)p * NBIN;
    const uint32_t k0 = (uint32_t)kptr[0];
    __shared__ uint32_t csum[256], cpre[256];
    const int top = NBIN - 1 - t * 4;
    uint32_t s = 0;
    #pragma unroll
    for (int j = 0; j < 4; ++j) s += h[top - j];
    csum[t] = s;
    __syncthreads();
    if (t == 0) { uint32_t run = 0; for (int i = 0; i < 256; ++i) { cpre[i] = run; run += csum[i]; } }
    __syncthreads();
    const uint32_t above = cpre[t];
    if (above < k0 && above + s >= k0) {
        uint32_t cum = above;
        for (int j = 0; j < 4; ++j) {
            int bin = top - j;
            uint32_t c = h[bin];
            cum += c;
            if (cum >= k0) { sel[p] = (uint32_t)bin; krem[p] = k0 - (cum - c); break; }
        }
    }
}

// descending scan of refinement hist: thr = lower edge of sub-bin holding rank krem
__global__ __launch_bounds__(256) void select2(
    const uint32_t* __restrict__ hist2, const uint32_t* __restrict__ Ru,
    const uint32_t* __restrict__ sel, const uint32_t* __restrict__ krem,
    float* __restrict__ thr)
{
    const int p = blockIdx.x, t = threadIdx.x;
    const uint32_t* h = hist2 + (size_t)p * NBIN;
    const uint32_t k0 = krem[p];
    const float R = __uint_as_float(Ru[p]);
    const float binw = 2.0f * R / (float)NBIN;
    const float lo = fmaf((float)(int)sel[p], binw, -R);
    const float subw = binw / (float)NBIN;
    if (t == 0) thr[p] = lo;                  // defensive default
    __shared__ uint32_t csum[256], cpre[256];
    const int top = NBIN - 1 - t * 4;
    uint32_t s = 0;
    #pragma unroll
    for (int j = 0; j < 4; ++j) s += h[top - j];
    csum[t] = s;
    __syncthreads();
    if (t == 0) { uint32_t run = 0; for (int i = 0; i < 256; ++i) { cpre[i] = run; run += csum[i]; } }
    __syncthreads();
    const uint32_t above = cpre[t];
    if (above < k0 && above + s >= k0) {
        uint32_t cum = above;
        for (int j = 0; j < 4; ++j) {
            int bin = top - j;
            uint32_t c = h[bin];
            cum += c;
            if (cum >= k0) { thr[p] = fmaf((float)bin, subw, lo); break; }
        }
    }
}

__global__ void finalize_kernel(const double* __restrict__ accum, float* __restrict__ out) {
    out[0] = (float)(accum[0] / ((double)B_ * (double)N_ * (double)N_));
}

extern "C" void kernel_launch(void* const* d_in, const int* in_sizes, int n_in,
                              void* d_out, int out_size, void* d_ws, size_t ws_size,
                              hipStream_t stream)
{
    const float* Xin = (const float*)d_in[0];
    const float* Xtg = (const float*)d_in[1];
    const int*  kptr = (const int*)d_in[3];
    float* out = (float*)d_out;

    char* ws = (char*)d_ws;
    double*   accum = (double*)  (ws + OFF_ACCUM);
    uint32_t* Ru    = (uint32_t*)(ws + OFF_RU);
    uint32_t* sel   = (uint32_t*)(ws + OFF_SEL);
    uint32_t* krem  = (uint32_t*)(ws + OFF_KREM);
    float*    thr   = (float*)   (ws + OFF_THR);
    uint32_t* hist  = (uint32_t*)(ws + OFF_HIST);
    uint32_t* hist2 = (uint32_t*)(ws + OFF_HIST2);
    ushort*   H     = (ushort*)  (ws + OFF_H);
    ushort*   L     = (ushort*)  (ws + OFF_L);
    if (ws_size < NEED_SMALL) return;
    const bool pre = (ws_size >= NEED_BIG);

    hipMemsetAsync(d_ws, 0, OFF_END, stream);   // accum,Ru,sel,krem,thr,hist,hist2

    dim3 blk(256);
    if (pre) {
        convert_kernel<<<dim3(1024, 2), blk, 0, stream>>>(Xin, Xtg, H, L, Ru);
        sim_kernel<0, true><<<dim3(NPAIRS, B_, 2), blk, 0, stream>>>(Xin, Xtg, H, L, Ru, hist, hist2, sel, thr, accum);
        select1<<<dim3(16), blk, 0, stream>>>(hist, kptr, sel, krem);
        sim_kernel<1, true><<<dim3(NPAIRS, B_, 2), blk, 0, stream>>>(Xin, Xtg, H, L, Ru, hist, hist2, sel, thr, accum);
        select2<<<dim3(16), blk, 0, stream>>>(hist2, Ru, sel, krem, thr);
        sim_kernel<2, true><<<dim3(NPAIRS, B_, 1), blk, 0, stream>>>(Xin, Xtg, H, L, Ru, hist, hist2, sel, thr, accum);
    } else {
        rownorm_kernel<<<dim3(16, 8), blk, 0, stream>>>(Xin, Xtg, Ru);
        sim_kernel<0, false><<<dim3(NPAIRS, B_, 2), blk, 0, stream>>>(Xin, Xtg, H, L, Ru, hist, hist2, sel, thr, accum);
        select1<<<dim3(16), blk, 0, stream>>>(hist, kptr, sel, krem);
        sim_kernel<1, false><<<dim3(NPAIRS, B_, 2), blk, 0, stream>>>(Xin, Xtg, H, L, Ru, hist, hist2, sel, thr, accum);
        select2<<<dim3(16), blk, 0, stream>>>(hist2, Ru, sel, krem, thr);
        sim_kernel<2, false><<<dim3(NPAIRS, B_, 1), blk, 0, stream>>>(Xin, Xtg, H, L, Ru, hist, hist2, sel, thr, accum);
    }
    finalize_kernel<<<1, 1, 0, stream>>>(accum, out);
}

// Round 5
// 161.060 us; speedup vs baseline: 13.8330x; 1.1037x over previous
//
#include <hip/hip_runtime.h>
#include <stdint.h>

#define N_ 2048
#define D_ 128
#define B_ 8
#define BT 128           // block tile
#define NT 16            // N_/BT
#define NPAIRS 136       // NT*(NT+1)/2 upper-triangle tile pairs
#define NBIN 1024

typedef __attribute__((ext_vector_type(8))) short short8;
typedef __attribute__((ext_vector_type(4))) float f32x4;

// ws layout (bytes)
#define OFF_ACCUM 0
#define OFF_RU    64
#define OFF_SEL   128
#define OFF_KREM  192
#define OFF_THR   256
#define OFF_HIST  512                        // 16*1024*4 = 64 KB (coarse)
#define OFF_HIST2 (512 + 16*NBIN*4)          // 64 KB (refinement)
#define OFF_END   (512 + 32*NBIN*4)
#define OFF_H     ((size_t)OFF_END)          // 16 panels * 2048*128 * 2B = 8 MB
#define OFF_L     (OFF_H + (size_t)8388608)  // 8 MB
#define NEED      (OFF_L + (size_t)8388608)

// f32 -> bf16 bits, round-to-nearest-even (finite inputs only)
__device__ __forceinline__ uint32_t bf16_rne(float x) {
    uint32_t u = __float_as_uint(x);
    return (u + 0x7fffu + ((u >> 16) & 1u)) >> 16;
}
// coarse linear bin — identical expression in MODE0 and MODE1
__device__ __forceinline__ int binof(float v, float R, float scl) {
    int b = (int)((v + R) * scl);
    if (b < 0) b = 0;
    if (b >= NBIN) b = NBIN - 1;
    return b;
}

// Fragment-major panel layout: panel p (2048 rows x 128 k) stored as
// [128 row-tiles rt][4 k-tiles kt] fragments of 1KB; within a fragment,
// lane-slot order: lane l = (r&15) + ((k>>3)&3)*16 owns 16B (8 bf16) at l*16.
// A wave loads its MFMA operand as one dwordx4 at frag_base + lane*16.

// 128x128 tile (ti,tj) of sim via split-bf16 MFMA (hh + hl + lh), direct from
// global fragments — no LDS, no barriers. 4 waves (2x2), each 64x64.
__device__ __forceinline__ void gemm_tile(const ushort* __restrict__ Hp,
        const ushort* __restrict__ Lp, int ti, int tj, f32x4 acc[4][4], int t)
{
    const int lane = t & 63;
    const int wv = t >> 6, wr = wv >> 1, wc = wv & 1;
    const ushort* AH = Hp + (size_t)(ti*8 + wr*4)*2048 + lane*8;
    const ushort* AL = Lp + (size_t)(ti*8 + wr*4)*2048 + lane*8;
    const ushort* BH = Hp + (size_t)(tj*8 + wc*4)*2048 + lane*8;
    const ushort* BL = Lp + (size_t)(tj*8 + wc*4)*2048 + lane*8;

    #pragma unroll
    for (int mm = 0; mm < 4; ++mm)
        #pragma unroll
        for (int nn = 0; nn < 4; ++nn)
            acc[mm][nn] = f32x4{0.f, 0.f, 0.f, 0.f};

    #pragma unroll 2
    for (int kt = 0; kt < 4; ++kt) {
        short8 ah[4], al[4], bh[4], bl[4];
        #pragma unroll
        for (int mm = 0; mm < 4; ++mm) {
            ah[mm] = *(const short8*)&AH[mm*2048 + kt*512];
            al[mm] = *(const short8*)&AL[mm*2048 + kt*512];
            bh[mm] = *(const short8*)&BH[mm*2048 + kt*512];
            bl[mm] = *(const short8*)&BL[mm*2048 + kt*512];
        }
        #pragma unroll
        for (int mm = 0; mm < 4; ++mm)
            #pragma unroll
            for (int nn = 0; nn < 4; ++nn) {
                acc[mm][nn] = __builtin_amdgcn_mfma_f32_16x16x32_bf16(ah[mm], bh[nn], acc[mm][nn], 0, 0, 0);
                acc[mm][nn] = __builtin_amdgcn_mfma_f32_16x16x32_bf16(ah[mm], bl[nn], acc[mm][nn], 0, 0, 0);
                acc[mm][nn] = __builtin_amdgcn_mfma_f32_16x16x32_bf16(al[mm], bh[nn], acc[mm][nn], 0, 0, 0);
            }
    }
}

// f32 -> (hi,lo) bf16 fragment-major panels + fused per-pair max row-norm^2
__global__ __launch_bounds__(256) void convert_kernel(
    const float* __restrict__ Xin, const float* __restrict__ Xtg,
    ushort* __restrict__ H, ushort* __restrict__ L, uint32_t* __restrict__ Ru)
{
    const int t = threadIdx.x;
    const int m = blockIdx.y;
    const float* X = m ? Xtg : Xin;
    const size_t e8 = (size_t)blockIdx.x * 256 + t;
    const size_t idx = e8 * 8;                     // element index within matrix
    const int b = (int)(e8 >> 15);                 // 32768 groups per batch item
    const int r = (int)((idx >> 7) & 2047);
    const int k = (int)(idx & 127);

    float4 v0 = *(const float4*)&X[idx];
    float4 v1 = *(const float4*)&X[idx + 4];
    ushort h8[8], l8[8];
    float vv[8] = {v0.x, v0.y, v0.z, v0.w, v1.x, v1.y, v1.z, v1.w};
    float s = 0.f;
    #pragma unroll
    for (int j = 0; j < 8; ++j) {
        uint32_t h = bf16_rne(vv[j]);
        h8[j] = (ushort)h;
        l8[j] = (ushort)bf16_rne(vv[j] - __uint_as_float(h << 16));
        s += vv[j] * vv[j];
    }
    const int p = m * B_ + b;
    const size_t off = (size_t)p * (N_*D_)
        + (size_t)((r >> 4) * 4 + (k >> 5)) * 512
        + (size_t)((r & 15) + ((k >> 3) & 3) * 16) * 8;
    *(short8*)&H[off] = *(short8*)h8;
    *(short8*)&L[off] = *(short8*)l8;

    // rownorm: 16 consecutive lanes cover one row (128 k)
    s += __shfl_xor(s, 1); s += __shfl_xor(s, 2); s += __shfl_xor(s, 4); s += __shfl_xor(s, 8);
    s = fmaxf(s, __shfl_xor(s, 16)); s = fmaxf(s, __shfl_xor(s, 32));
    __shared__ float wm[4];
    if ((t & 63) == 0) wm[t >> 6] = s;
    __syncthreads();
    if (t == 0) {
        float mx = fmaxf(fmaxf(wm[0], wm[1]), fmaxf(wm[2], wm[3]));
        atomicMax(&Ru[p], __float_as_uint(mx));   // positive: uint order == float order
    }
}

// MODE 0: coarse linear 1024-bin LDS hist -> weighted flush to hist
// MODE 1: refinement 1024-bin hist over selected coarse bin's range -> hist2
// MODE 2: masked MSE over both matrices -> double atomic
// Grid is 1-D; low bits of blockIdx.x carry the pair index so each pair's
// panels stay hot in one XCD's L2 (dispatch round-robins id%8 -> XCD).
template<int MODE>
__global__ __launch_bounds__(256) void sim_kernel(
    const ushort* __restrict__ H, const ushort* __restrict__ L,
    const uint32_t* __restrict__ Ru, uint32_t* __restrict__ hist,
    uint32_t* __restrict__ hist2, const uint32_t* __restrict__ sel,
    const float* __restrict__ thr, double* __restrict__ accum)
{
    __shared__ uint32_t lh[(MODE <= 1) ? NBIN : 1];
    const int t = threadIdx.x;
    const int id = blockIdx.x;
    const int p    = (MODE == 2) ? (id & 7) : (id & 15);   // MODE2: p = b (input side)
    const int tile = (MODE == 2) ? (id >> 3) : (id >> 4);

    if (MODE <= 1) {
        #pragma unroll
        for (int i = t; i < NBIN; i += 256) lh[i] = 0;
        __syncthreads();
    }

    int rem = tile, ti = 0;
    while (true) { int len = NT - ti; if (rem < len) break; rem -= len; ++ti; }
    const int tj = ti + rem;
    const uint32_t w = (ti == tj) ? 1u : 2u;

    const ushort* Hp = H + (size_t)p * (N_*D_);
    const ushort* Lp = L + (size_t)p * (N_*D_);

    f32x4 acc[4][4];
    gemm_tile(Hp, Lp, ti, tj, acc, t);

    if (MODE == 0) {
        const float R = __uint_as_float(Ru[p]);
        const float scl = (float)NBIN / (2.0f * R);
        #pragma unroll
        for (int mm = 0; mm < 4; ++mm)
            #pragma unroll
            for (int nn = 0; nn < 4; ++nn)
                #pragma unroll
                for (int r = 0; r < 4; ++r)
                    atomicAdd(&lh[binof(acc[mm][nn][r], R, scl)], 1u);
        __syncthreads();
        uint32_t* gh = hist + (size_t)p * NBIN;
        for (int i = t; i < NBIN; i += 256) {
            uint32_t c = lh[i];
            if (c) atomicAdd(&gh[i], c * w);
        }
    } else if (MODE == 1) {
        const float R = __uint_as_float(Ru[p]);
        const float scl = (float)NBIN / (2.0f * R);
        const float binw = 2.0f * R / (float)NBIN;
        const int s = (int)sel[p];
        const float lo = fmaf((float)s, binw, -R);
        const float scl2 = (float)NBIN / binw;
        #pragma unroll
        for (int mm = 0; mm < 4; ++mm)
            #pragma unroll
            for (int nn = 0; nn < 4; ++nn)
                #pragma unroll
                for (int r = 0; r < 4; ++r) {
                    float v = acc[mm][nn][r];
                    if (binof(v, R, scl) == s) {
                        int j = (int)((v - lo) * scl2);
                        if (j < 0) j = 0;
                        if (j >= NBIN) j = NBIN - 1;
                        atomicAdd(&lh[j], 1u);
                    }
                }
        __syncthreads();
        uint32_t* gh = hist2 + (size_t)p * NBIN;
        for (int i = t; i < NBIN; i += 256) {
            uint32_t c = lh[i];
            if (c) atomicAdd(&gh[i], c * w);
        }
    } else {
        f32x4 accT[4][4];
        const ushort* HpT = H + (size_t)(B_ + p) * (N_*D_);
        const ushort* LpT = L + (size_t)(B_ + p) * (N_*D_);
        gemm_tile(HpT, LpT, ti, tj, accT, t);
        const float thrI = thr[p], thrT = thr[B_ + p];
        float local = 0.f;
        #pragma unroll
        for (int mm = 0; mm < 4; ++mm)
            #pragma unroll
            for (int nn = 0; nn < 4; ++nn)
                #pragma unroll
                for (int r = 0; r < 4; ++r) {
                    float vI = acc[mm][nn][r],  aI = (vI >= thrI) ? vI : 0.f;
                    float vT = accT[mm][nn][r], aT = (vT >= thrT) ? vT : 0.f;
                    float d = aI - aT;
                    local += d * d;
                }
        local *= (float)w;
        #pragma unroll
        for (int off = 32; off; off >>= 1) local += __shfl_down(local, off);
        __shared__ float wsum[4];
        if ((t & 63) == 0) wsum[t >> 6] = local;
        __syncthreads();
        if (t == 0) {
            double s2 = (double)wsum[0] + (double)wsum[1] + (double)wsum[2] + (double)wsum[3];
            atomicAdd(accum, s2);
        }
    }
}

// descending scan of coarse hist: bracket bin + remaining rank within it
__global__ __launch_bounds__(256) void select1(
    const uint32_t* __restrict__ hist, const int* __restrict__ kptr,
    uint32_t* __restrict__ sel, uint32_t* __restrict__ krem)
{
    const int p = blockIdx.x, t = threadIdx.x;
    const uint32_t* h = hist + (size_t)p * NBIN;
    const uint32_t k0 = (uint32_t)kptr[0];
    __shared__ uint32_t csum[256], cpre[256];
    const int top = NBIN - 1 - t * 4;
    uint32_t s = 0;
    #pragma unroll
    for (int j = 0; j < 4; ++j) s += h[top - j];
    csum[t] = s;
    __syncthreads();
    if (t == 0) { uint32_t run = 0; for (int i = 0; i < 256; ++i) { cpre[i] = run; run += csum[i]; } }
    __syncthreads();
    const uint32_t above = cpre[t];
    if (above < k0 && above + s >= k0) {
        uint32_t cum = above;
        for (int j = 0; j < 4; ++j) {
            int bin = top - j;
            uint32_t c = h[bin];
            cum += c;
            if (cum >= k0) { sel[p] = (uint32_t)bin; krem[p] = k0 - (cum - c); break; }
        }
    }
}

// descending scan of refinement hist: thr = lower edge of sub-bin holding rank krem
__global__ __launch_bounds__(256) void select2(
    const uint32_t* __restrict__ hist2, const uint32_t* __restrict__ Ru,
    const uint32_t* __restrict__ sel, const uint32_t* __restrict__ krem,
    float* __restrict__ thr)
{
    const int p = blockIdx.x, t = threadIdx.x;
    const uint32_t* h = hist2 + (size_t)p * NBIN;
    const uint32_t k0 = krem[p];
    const float R = __uint_as_float(Ru[p]);
    const float binw = 2.0f * R / (float)NBIN;
    const float lo = fmaf((float)(int)sel[p], binw, -R);
    const float subw = binw / (float)NBIN;
    if (t == 0) thr[p] = lo;                  // defensive default
    __shared__ uint32_t csum[256], cpre[256];
    const int top = NBIN - 1 - t * 4;
    uint32_t s = 0;
    #pragma unroll
    for (int j = 0; j < 4; ++j) s += h[top - j];
    csum[t] = s;
    __syncthreads();
    if (t == 0) { uint32_t run = 0; for (int i = 0; i < 256; ++i) { cpre[i] = run; run += csum[i]; } }
    __syncthreads();
    const uint32_t above = cpre[t];
    if (above < k0 && above + s >= k0) {
        uint32_t cum = above;
        for (int j = 0; j < 4; ++j) {
            int bin = top - j;
            uint32_t c = h[bin];
            cum += c;
            if (cum >= k0) { thr[p] = fmaf((float)bin, subw, lo); break; }
        }
    }
}

__global__ void finalize_kernel(const double* __restrict__ accum, float* __restrict__ out) {
    out[0] = (float)(accum[0] / ((double)B_ * (double)N_ * (double)N_));
}

extern "C" void kernel_launch(void* const* d_in, const int* in_sizes, int n_in,
                              void* d_out, int out_size, void* d_ws, size_t ws_size,
                              hipStream_t stream)
{
    const float* Xin = (const float*)d_in[0];
    const float* Xtg = (const float*)d_in[1];
    const int*  kptr = (const int*)d_in[3];
    float* out = (float*)d_out;

    char* ws = (char*)d_ws;
    double*   accum = (double*)  (ws + OFF_ACCUM);
    uint32_t* Ru    = (uint32_t*)(ws + OFF_RU);
    uint32_t* sel   = (uint32_t*)(ws + OFF_SEL);
    uint32_t* krem  = (uint32_t*)(ws + OFF_KREM);
    float*    thr   = (float*)   (ws + OFF_THR);
    uint32_t* hist  = (uint32_t*)(ws + OFF_HIST);
    uint32_t* hist2 = (uint32_t*)(ws + OFF_HIST2);
    ushort*   H     = (ushort*)  (ws + OFF_H);
    ushort*   L     = (ushort*)  (ws + OFF_L);
    if (ws_size < NEED) return;

    hipMemsetAsync(d_ws, 0, OFF_END, stream);   // accum,Ru,sel,krem,thr,hist,hist2

    dim3 blk(256);
    convert_kernel<<<dim3(1024, 2), blk, 0, stream>>>(Xin, Xtg, H, L, Ru);
    sim_kernel<0><<<dim3(NPAIRS * 16), blk, 0, stream>>>(H, L, Ru, hist, hist2, sel, thr, accum);
    select1<<<dim3(16), blk, 0, stream>>>(hist, kptr, sel, krem);
    sim_kernel<1><<<dim3(NPAIRS * 16), blk, 0, stream>>>(H, L, Ru, hist, hist2, sel, thr, accum);
    select2<<<dim3(16), blk, 0, stream>>>(hist2, Ru, sel, krem, thr);
    sim_kernel<2><<<dim3(NPAIRS * 8), blk, 0, stream>>>(H, L, Ru, hist, hist2, sel, thr, accum);
    finalize_kernel<<<1, 1, 0, stream>>>(accum, out);
}